// Round 15
// baseline (206.126 us; speedup 1.0000x reference)
//
#include <hip/hip_runtime.h>
#include <hip/hip_bf16.h>

#define DD   4096   // hidden dim
#define NE   8      // experts
#define NR   16     // lora rank
#define NTOK 8192   // B*S
#define NDO  4096   // output dim
#define TAU  0.01f  // ambiguity margin (bf16-x routing err, r9-r14-validated)
#define MAXFLAG 8000
// SCALING = 16/16 = 1.0

typedef __attribute__((ext_vector_type(8))) __bf16 bf16x8;
typedef __attribute__((ext_vector_type(4))) __bf16 bf16x4;
typedef __attribute__((ext_vector_type(4))) float  f32x4;

__device__ __forceinline__ bf16x8 to_bf16x8(float4 a, float4 b) {
    bf16x8 r;
    r[0] = (__bf16)a.x; r[1] = (__bf16)a.y; r[2] = (__bf16)a.z; r[3] = (__bf16)a.w;
    r[4] = (__bf16)b.x; r[5] = (__bf16)b.y; r[6] = (__bf16)b.z; r[7] = (__bf16)b.w;
    return r;
}

__device__ __forceinline__ bf16x8 zero_frag() {
    bf16x8 z;
    #pragma unroll
    for (int j = 0; j < 8; j++) z[j] = (__bf16)0.0f;
    return z;
}

// ---------------- k_prep_w: weight conversions (tiny, ~2.2MB total) ----------------
__global__ __launch_bounds__(256) void k_prep_w(const float* __restrict__ rw,
                                                const float* __restrict__ Am,
                                                const float* __restrict__ Bw,
                                                __bf16* __restrict__ rwhl,
                                                __bf16* __restrict__ Ab,
                                                __bf16* __restrict__ Bwb) {
    const int b = blockIdx.x;
    if (b < 1024) {
        const int o = (b & 511) * 1024 + threadIdx.x * 4;
        const float4 v = *(const float4*)(((b < 512) ? Bw : Am) + o);
        bf16x4 p;
        p[0] = (__bf16)v.x; p[1] = (__bf16)v.y; p[2] = (__bf16)v.z; p[3] = (__bf16)v.w;
        *(bf16x4*)(((b < 512) ? Bwb : Ab) + o) = p;
    } else {
        const int o = (b - 1024) * 1024 + threadIdx.x * 4;   // 0..65535
        const int row = o >> 12, k = o & 4095;
        const float4 v = *(const float4*)(rw + ((size_t)(row & 7) << 12) + k);
        bf16x4 p;
        if (row < 8) {
            p[0] = (__bf16)v.x; p[1] = (__bf16)v.y; p[2] = (__bf16)v.z; p[3] = (__bf16)v.w;
        } else {
            p[0] = (__bf16)(v.x - (float)(__bf16)v.x);
            p[1] = (__bf16)(v.y - (float)(__bf16)v.y);
            p[2] = (__bf16)(v.z - (float)(__bf16)v.z);
            p[3] = (__bf16)(v.w - (float)(__bf16)v.w);
        }
        *(bf16x4*)(rwhl + o) = p;
    }
}

// ---------------- k_rh: FUSED routing + all-expert h partials ----------------
// r12 route_part geometry verbatim (2048 blocks x 4 waves, block = 16 tok x
// K-quarter), plus 8 expert MFMAs per k-chunk (Ab L2-hot). One x pass feeds
// both logits and h. Partials: pbufL[kg][tok][e], pbufH[kg][tok][e][r].
__global__ __launch_bounds__(256, 1) void k_rh(const float* __restrict__ x,
                                               const __bf16* __restrict__ rwhl,
                                               const __bf16* __restrict__ Ab,
                                               float* __restrict__ pbufL,
                                               float* __restrict__ pbufH) {
    const int tg = blockIdx.x >> 2;           // token group (16 tokens)
    const int kg = blockIdx.x & 3;            // K-quarter
    const int t0 = tg * 16;
    const int wv = threadIdx.x >> 6;          // 0..3
    const int lane = threadIdx.x & 63;
    const int m = lane & 15;
    const int half = lane >> 4;

    const float*  xrow = x    + (size_t)(t0 + m) * DD;
    const __bf16* wrow = rwhl + (size_t)m * DD;
    const int kbase = kg * 1024 + wv * 256;

    f32x4 accR = {0.f, 0.f, 0.f, 0.f};
    f32x4 accE[NE];
    #pragma unroll
    for (int e = 0; e < NE; e++) accE[e] = (f32x4){0.f, 0.f, 0.f, 0.f};

    #pragma unroll
    for (int ks = 0; ks < 8; ks++) {
        const int k0 = kbase + ks * 32 + half * 8;
        const float4 xa = *(const float4*)(xrow + k0);
        const float4 xc = *(const float4*)(xrow + k0 + 4);
        const bf16x8 wb = *(const bf16x8*)(wrow + k0);
        const bf16x8 xf = to_bf16x8(xa, xc);
        accR = __builtin_amdgcn_mfma_f32_16x16x32_bf16(xf, wb, accR, 0, 0, 0);
        #pragma unroll
        for (int e = 0; e < NE; e++) {
            const bf16x8 af = *(const bf16x8*)(Ab + ((size_t)e * NR + m) * DD + k0);
            accE[e] = __builtin_amdgcn_mfma_f32_16x16x32_bf16(xf, af, accE[e], 0, 0, 0);
        }
    }

    // ---- logits reduce (r12 form): C row = token, col = rwhl row
    __shared__ float Lred[4][16][17];
    #pragma unroll
    for (int r = 0; r < 4; r++)
        Lred[wv][half * 4 + r][m] = accR[r];
    __syncthreads();

    if (threadIdx.x < 128) {
        const int t = threadIdx.x >> 3, ee = threadIdx.x & 7;
        float s = 0.f;
        #pragma unroll
        for (int w = 0; w < 4; w++) s += Lred[w][t][ee] + Lred[w][t][ee + 8];
        pbufL[((size_t)kg * NTOK + t0 + t) * NE + ee] = s;
    }

    // ---- h reduce: 4 passes of 2 experts through a 9KB LDS buffer
    __shared__ float hbuf[4][16][2][17];
    #pragma unroll
    for (int eg = 0; eg < 4; eg++) {
        __syncthreads();                      // prior readers done
        #pragma unroll
        for (int r = 0; r < 4; r++) {
            hbuf[wv][half * 4 + r][0][m] = accE[eg * 2][r];
            hbuf[wv][half * 4 + r][1][m] = accE[eg * 2 + 1][r];
        }
        __syncthreads();
        #pragma unroll
        for (int q = 0; q < 2; q++) {
            const int idx = q * 256 + threadIdx.x;    // t(4b) e2(1b) r(4b)
            const int t = idx >> 5, e2 = (idx >> 4) & 1, r = idx & 15;
            const float s = hbuf[0][t][e2][r] + hbuf[1][t][e2][r]
                          + hbuf[2][t][e2][r] + hbuf[3][t][e2][r];
            pbufH[(((size_t)kg * NTOK + t0 + t) * NE + eg * 2 + e2) * NR + r] = s;
        }
    }
}

// ---------------- k_fin: argmax + TAU flag + binning + wh = w*h[e*] ----------------
// 32 blocks x 256 thr; thread = token.
__global__ __launch_bounds__(256) void k_fin(const float* __restrict__ pbufL,
                                             const float* __restrict__ pbufH,
                                             float* __restrict__ w_arr,
                                             __bf16* __restrict__ wh,
                                             int*   __restrict__ token_list,
                                             int*   __restrict__ count,
                                             int*   __restrict__ nflag,
                                             int*   __restrict__ flaglist) {
    const int tok = blockIdx.x * 256 + threadIdx.x;
    float l[NE];
    #pragma unroll
    for (int e = 0; e < NE; e++)
        l[e] = pbufL[((size_t)0 * NTOK + tok) * NE + e]
             + pbufL[((size_t)1 * NTOK + tok) * NE + e]
             + pbufL[((size_t)2 * NTOK + tok) * NE + e]
             + pbufL[((size_t)3 * NTOK + tok) * NE + e];

    float best = -1e30f, second = -1e30f; int be = 0;
    #pragma unroll
    for (int e = 0; e < NE; e++) {
        if (l[e] > best) { second = best; best = l[e]; be = e; }
        else if (l[e] > second) { second = l[e]; }
    }
    w_arr[tok] = best;
    if (best - second < TAU) {
        const int p = atomicAdd(nflag, 1);
        if (p < MAXFLAG) flaglist[p] = tok;   // wh below is approx; k_fix rewrites
    } else {
        const int p = atomicAdd(&count[be], 1);
        token_list[be * NTOK + p] = tok;
    }

    float h[NR];
    #pragma unroll
    for (int r = 0; r < NR; r++) h[r] = 0.f;
    #pragma unroll
    for (int g = 0; g < 4; g++) {
        #pragma unroll
        for (int r = 0; r < NR; r++)
            h[r] += pbufH[(((size_t)g * NTOK + tok) * NE + be) * NR + r];
    }
    bf16x8 w0, w1;
    #pragma unroll
    for (int r = 0; r < 8; r++) {
        w0[r] = (__bf16)(h[r] * best);
        w1[r] = (__bf16)(h[r + 8] * best);
    }
    *(bf16x8*)(wh + (size_t)tok * NR)     = w0;
    *(bf16x8*)(wh + (size_t)tok * NR + 8) = w1;
}

// ---------------- k_fix: exact f64 re-route + wh recompute for flagged ----------------
__global__ __launch_bounds__(256) void k_fix(const float* __restrict__ x,
                                             const float* __restrict__ rw,
                                             const __bf16* __restrict__ Ab,
                                             float* __restrict__ w_arr,
                                             __bf16* __restrict__ wh,
                                             int*   __restrict__ token_list,
                                             int*   __restrict__ count,
                                             const int* __restrict__ nflag,
                                             const int* __restrict__ flaglist) {
    const int wv   = threadIdx.x >> 6;
    const int lane = threadIdx.x & 63;
    int n = *nflag; if (n > MAXFLAG) n = MAXFLAG;

    for (int idx = blockIdx.x * 4 + wv; idx < n; idx += 512) {
        const int tok = flaglist[idx];
        const float* xp = x + (size_t)tok * DD;
        double acc[NE];
        #pragma unroll
        for (int e = 0; e < NE; e++) acc[e] = 0.0;
        for (int i = 0; i < 16; i++) {
            const int d4 = (i * 64 + lane) * 4;
            const float4 xv = *(const float4*)(xp + d4);
            const double x0 = xv.x, x1 = xv.y, x2 = xv.z, x3 = xv.w;
            #pragma unroll
            for (int e = 0; e < NE; e++) {
                const float4 wv4 = *(const float4*)(rw + (size_t)e * DD + d4);
                acc[e] = fma(x0, (double)wv4.x, acc[e]);
                acc[e] = fma(x1, (double)wv4.y, acc[e]);
                acc[e] = fma(x2, (double)wv4.z, acc[e]);
                acc[e] = fma(x3, (double)wv4.w, acc[e]);
            }
        }
        #pragma unroll
        for (int off = 32; off > 0; off >>= 1)
            #pragma unroll
            for (int e = 0; e < NE; e++)
                acc[e] += __shfl_xor(acc[e], off, 64);

        // every lane has identical full sums -> same argmax everywhere
        double best = acc[0]; int be = 0;
        #pragma unroll
        for (int e = 1; e < NE; e++) if (acc[e] > best) { best = acc[e]; be = e; }
        const float bw = (float)best;

        // recompute h[e*] (f32 on bf16-A, matches main-path precision class)
        float h[NR];
        #pragma unroll
        for (int r = 0; r < NR; r++) h[r] = 0.f;
        const __bf16* abase = Ab + (size_t)be * NR * DD;
        for (int i = 0; i < 64; i++) {
            const int k = i * 64 + lane;
            const float xv = xp[k];
            #pragma unroll
            for (int r = 0; r < NR; r++)
                h[r] = fmaf(xv, (float)abase[(size_t)r * DD + k], h[r]);
        }
        #pragma unroll
        for (int off = 32; off > 0; off >>= 1)
            #pragma unroll
            for (int r = 0; r < NR; r++)
                h[r] += __shfl_xor(h[r], off, 64);

        if (lane == 0) {
            w_arr[tok] = bw;
            const int pos = atomicAdd(&count[be], 1);
            token_list[be * NTOK + pos] = tok;
            #pragma unroll
            for (int r = 0; r < NR; r++)
                wh[(size_t)tok * NR + r] = (__bf16)(h[r] * bw);
        }
    }
}

// ---------------- k_out: 64-token B-amortized MFMA + row-contiguous epilogue ----------------
// 4096 blocks (8e x 64 slots x 8 col-chunks) x 256 thr (4 waves). Block = 64
// tokens x 512 cols in 4 LDS passes of 128 cols (35KB tile -> 4 blocks/CU).
// B-frag loaded once serves 4 token-subtiles (B L2 traffic 512MB -> 16MB).
// Epilogue: f32x4 nontemporal stores, 512B contiguous per row-round.
__global__ __launch_bounds__(256, 1) void k_out(const __bf16* __restrict__ Bwb,
                                                const __bf16* __restrict__ wh,
                                                const int*   __restrict__ token_list,
                                                const int*   __restrict__ count,
                                                float* __restrict__ out) {
    const int bx    = blockIdx.x;
    const int e     = bx >> 9;
    const int slot  = (bx >> 3) & 63;
    const int chunk = bx & 7;
    const int cnt   = count[e];
    const int base  = slot * 64;
    if (base >= cnt) return;

    const int wv   = threadIdx.x >> 6;        // 0..3
    const int lane = threadIdx.x & 63;
    const int m    = lane & 15;
    const int half = lane >> 4;
    const int h2   = (half < 2) ? half : 0;
    const bf16x8 zf = zero_frag();

    // 4 token-subtiles: wh B-operand frags (K=16 zero-padded to 32)
    bf16x8 a2[4];
    #pragma unroll
    for (int s = 0; s < 4; s++) {
        const int idx = base + s * 16 + m;
        const bool v  = idx < cnt;
        const int tk  = v ? token_list[e * NTOK + idx] : 0;
        a2[s] = (half < 2 && v) ? *(const bf16x8*)(wh + (size_t)tk * NR + half * 8) : zf;
    }

    __shared__ float tile[64][136];           // 35KB -> 4 blocks/CU
    const __bf16* bwe = Bwb + (size_t)e * NDO * NR;
    const f32x4 zero4 = {0.f, 0.f, 0.f, 0.f};

    for (int hf = 0; hf < 4; hf++) {
        const int cb = chunk * 512 + hf * 128;    // global col base
        if (hf) __syncthreads();                  // prior stores done reading tile
        #pragma unroll
        for (int i = 0; i < 2; i++) {
            const int oc = cb + (wv * 2 + i) * 16;
            const bf16x8 b2 = (half < 2)
                ? *(const bf16x8*)(bwe + (size_t)(oc + m) * NR + h2 * 8)
                : zf;
            #pragma unroll
            for (int s = 0; s < 4; s++) {
                // swapped operands: C col = token (m), row = o (half*4+reg)
                const f32x4 d = __builtin_amdgcn_mfma_f32_16x16x32_bf16(b2, a2[s], zero4, 0, 0, 0);
                *(f32x4*)&tile[s * 16 + m][(wv * 2 + i) * 16 + half * 4] = d;
            }
        }
        __syncthreads();
        // 8 rows in parallel (32 lanes x f32x4 = 512B contiguous per row)
        #pragma unroll
        for (int it = 0; it < 8; it++) {
            const int r  = it * 8 + (threadIdx.x >> 5);
            const int ir = base + r;
            if (ir < cnt) {
                const int tk = token_list[e * NTOK + ir];
                const int c  = (threadIdx.x & 31) * 4;
                const f32x4 v = *(const f32x4*)&tile[r][c];
                __builtin_nontemporal_store(v, (f32x4*)(out + (size_t)tk * NDO + cb + c));
            }
        }
    }
}

// ---------------- launcher ----------------
extern "C" void kernel_launch(void* const* d_in, const int* in_sizes, int n_in,
                              void* d_out, int out_size, void* d_ws, size_t ws_size,
                              hipStream_t stream) {
    const float* x  = (const float*)d_in[0];
    const float* rw = (const float*)d_in[1];
    const float* Am = (const float*)d_in[2];
    const float* Bw = (const float*)d_in[3];
    float* out = (float*)d_out;

    char* ws = (char*)d_ws;
    int*   count      = (int*)ws;                           // 8 ints @ 0
    int*   nflag      = (int*)(ws + 32);                    // 1 int
    float* w_arr      = (float*)(ws + 512);                 // 8192 f32   -> ends 33280
    int*   flaglist   = (int*)(ws + 33280);                 // 8000 ints  -> ends 65280
    int*   token_list = (int*)(ws + 65536);                 // 64K ints   -> ends 327680
    __bf16* wh        = (__bf16*)(ws + 327680);             // 8192x16 bf16 -> ends 589824
    __bf16* rwhl      = (__bf16*)(ws + 589824);             // 128KB      -> ends 720896
    __bf16* Bwb       = (__bf16*)(ws + 720896);             // 1MB        -> ends 1769472
    __bf16* Ab        = (__bf16*)(ws + 1769472);            // 1MB        -> ends 2818048
    float*  pbufL     = (float*)(ws + 3145728);             // 1MB        -> ends 4194304
    float*  pbufH     = (float*)(ws + 4194304);             // 16MB       -> ends 20971520

    hipMemsetAsync(ws, 0, 64, stream);                      // count + nflag
    hipLaunchKernelGGL(k_prep_w, dim3(1088), dim3(256), 0, stream, rw, Am, Bw, rwhl, Ab, Bwb);
    hipLaunchKernelGGL(k_rh,     dim3(2048), dim3(256), 0, stream, x, rwhl, Ab, pbufL, pbufH);
    hipLaunchKernelGGL(k_fin,    dim3(32),   dim3(256), 0, stream, pbufL, pbufH, w_arr, wh, token_list, count, nflag, flaglist);
    hipLaunchKernelGGL(k_fix,    dim3(128),  dim3(256), 0, stream, x, rw, Ab, w_arr, wh, token_list, count, nflag, flaglist);
    hipLaunchKernelGGL(k_out,    dim3(4096), dim3(256), 0, stream, Bwb, wh, token_list, count, out);
}